// Round 8
// baseline (1510.633 us; speedup 1.0000x reference)
//
#include <hip/hip_runtime.h>

// GCN: 7x GCNConv (first 6 with ReLU+BN training-mode), then global_add_pool.
// N=16384 nodes, E=131072 edges, 64 graphs. fp32 in/out, **fp16 internal** + MFMA
// (f16 ulp 2^-11 vs bf16 2^-8: 8x finer -> absmax margin; same MFMA rate).
// agg on the narrow side per layer (agg is linear). BN4->L5-agg and BN6->GEMV
// folds kept (fp32-register); other BN layers: fused stats->apply pass.
// GEMM: 256x256 8-phase schedule (R6-measured variant: 990 TF on L2 shape).

#define NN 16384
#define NE 131072
#define NG 64

typedef unsigned int u32;
typedef unsigned short u16;
typedef __attribute__((ext_vector_type(8))) _Float16 half8;
typedef __attribute__((ext_vector_type(4))) float f32x4;
typedef __attribute__((ext_vector_type(8))) u16 us8;
typedef __attribute__((ext_vector_type(4))) u16 us4;
typedef __attribute__((ext_vector_type(2))) u16 us2;

#define AS1(p) ((const __attribute__((address_space(1))) void*)(p))
#define AS3(p) ((__attribute__((address_space(3))) void*)(p))

// f16 <-> f32 (RNE on the way down)
__device__ __forceinline__ float b2f(u16 h) {
    _Float16 x = __builtin_bit_cast(_Float16, h);
    return (float)x;
}
__device__ __forceinline__ u16 f2b(float f) {
    _Float16 x = (_Float16)f;
    return __builtin_bit_cast(u16, x);
}

template <int VW> struct VecU;
template <> struct VecU<8> { typedef us8 T; };
template <> struct VecU<4> { typedef us4 T; };
template <> struct VecU<2> { typedef us2 T; };
template <> struct VecU<1> { typedef u16 T; };

template <int VW>
__device__ __forceinline__ void loadf(const u16* p, float* f) {
    typename VecU<VW>::T v = *(const typename VecU<VW>::T*)p;
    if constexpr (VW == 1) {
        f[0] = b2f((u16)v);
    } else {
        #pragma unroll
        for (int j = 0; j < VW; ++j) f[j] = b2f(v[j]);
    }
}
template <int VW>
__device__ __forceinline__ void storef(u16* p, const float* f) {
    typename VecU<VW>::T v;
    if constexpr (VW == 1) {
        v = f2b(f[0]);
    } else {
        #pragma unroll
        for (int j = 0; j < VW; ++j) v[j] = f2b(f[j]);
    }
    *(typename VecU<VW>::T*)p = v;
}

// ---------- graph prep ----------
__global__ void k_degi(const int* __restrict__ dst, int* __restrict__ deg) {
    int e = blockIdx.x * 256 + threadIdx.x;
    if (e < NE) atomicAdd(&deg[dst[e]], 1);
}
__global__ void k_dinv(const int* __restrict__ deg, float* __restrict__ dinv) {
    int i = blockIdx.x * 256 + threadIdx.x;
    if (i < NN) dinv[i] = rsqrtf((float)(deg[i] + 1));   // +1 self loop
}
__global__ void k_nrm(const int* __restrict__ src, const int* __restrict__ dst,
                      const float* __restrict__ dinv, float* __restrict__ nrm) {
    int e = blockIdx.x * 256 + threadIdx.x;
    if (e < NE) nrm[e] = dinv[src[e]] * dinv[dst[e]];
}
__global__ __launch_bounds__(1024) void k_scan(const int* __restrict__ deg, int* __restrict__ rowptr) {
    __shared__ int part[1024];
    int t = threadIdx.x;
    int base = t * 16;
    int s = 0;
    #pragma unroll
    for (int j = 0; j < 16; ++j) s += deg[base + j];
    part[t] = s;
    __syncthreads();
    for (int off = 1; off < 1024; off <<= 1) {
        int v = 0;
        if (t >= off) v = part[t - off];
        __syncthreads();
        part[t] += v;
        __syncthreads();
    }
    int run = part[t] - s;  // exclusive prefix
    for (int j = 0; j < 16; ++j) { rowptr[base + j] = run; run += deg[base + j]; }
    if (t == 1023) rowptr[NN] = run;
}
__global__ void k_place(const int* __restrict__ src, const int* __restrict__ dst,
                        const float* __restrict__ nrm, const int* __restrict__ rowptr,
                        int* __restrict__ cursor, int* __restrict__ csr_src,
                        float* __restrict__ csr_w) {
    int e = blockIdx.x * 256 + threadIdx.x;
    if (e >= NE) return;
    int d = dst[e];
    int p = rowptr[d] + atomicAdd(&cursor[d], 1);
    csr_src[p] = src[e];
    csr_w[p] = nrm[e];
}
// s_i = dinv_i^2 + sum of edge weights into i
__global__ void k_srow(const int* __restrict__ rowptr, const float* __restrict__ csr_w,
                       const float* __restrict__ dinv, float* __restrict__ svec) {
    int i = blockIdx.x * 256 + threadIdx.x;
    if (i >= NN) return;
    float s = dinv[i] * dinv[i];
    int r1 = rowptr[i + 1];
    for (int e = rowptr[i]; e < r1; ++e) s += csr_w[e];
    svec[i] = s;
}

// ---------- conversions ----------
__global__ void k_x2b(const float* __restrict__ x, u16* __restrict__ xp) {
    int idx = blockIdx.x * 256 + threadIdx.x;   // over NN*512
    int i = idx >> 9, c = idx & 511;
    float v = (c < 396) ? x[(size_t)i * 396 + c] : 0.f;
    xp[idx] = f2b(v);
}
// Wt[n][k] = f16(W[k][n]), K padded with zeros
__global__ void k_wt(const float* __restrict__ W, u16* __restrict__ Wt,
                     int Ksrc, int Kpad, int N) {
    __shared__ float t[32][33];
    int k0 = blockIdx.x * 32, n0 = blockIdx.y * 32;
    #pragma unroll
    for (int j = 0; j < 4; ++j) {
        int k = k0 + threadIdx.y + j * 8;
        float v = 0.f;
        if (k < Ksrc) v = W[(size_t)k * N + n0 + threadIdx.x];
        t[threadIdx.y + j * 8][threadIdx.x] = v;
    }
    __syncthreads();
    #pragma unroll
    for (int j = 0; j < 4; ++j) {
        int n = n0 + threadIdx.y + j * 8;
        int k = k0 + threadIdx.x;
        Wt[(size_t)n * Kpad + k] = f2b(t[threadIdx.x][threadIdx.y + j * 8]);
    }
}

// ---------- CSR gather aggregation (one block per node) ----------
// mode 0: out = acc ; mode 1: out = relu(acc + bias) ; mode 2: out = av*acc + s_i*bvv
template <int VW>
__global__ __launch_bounds__(256) void k_agg(const u16* __restrict__ in, u16* __restrict__ out,
                                             const int* __restrict__ rowptr,
                                             const int* __restrict__ csr_src,
                                             const float* __restrict__ csr_w,
                                             const float* __restrict__ dinv,
                                             const float* __restrict__ svec,
                                             const float* __restrict__ bias,
                                             const float* __restrict__ av,
                                             const float* __restrict__ bvv,
                                             int F, int mode) {
    int i = blockIdx.x;
    int c0 = threadIdx.x * VW;
    float acc[VW];
    float d2 = dinv[i]; d2 *= d2;
    {
        float v[VW];
        loadf<VW>(in + (size_t)i * F + c0, v);
        #pragma unroll
        for (int j = 0; j < VW; ++j) acc[j] = d2 * v[j];
    }
    int r0 = rowptr[i], r1 = rowptr[i + 1];
    for (int e = r0; e < r1; ++e) {
        int s = csr_src[e];
        float w = csr_w[e];
        float v[VW];
        loadf<VW>(in + (size_t)s * F + c0, v);
        #pragma unroll
        for (int j = 0; j < VW; ++j) acc[j] += w * v[j];
    }
    if (mode == 1) {
        #pragma unroll
        for (int j = 0; j < VW; ++j) acc[j] = fmaxf(acc[j] + bias[c0 + j], 0.f);
    } else if (mode == 2) {
        float si = svec[i];
        #pragma unroll
        for (int j = 0; j < VW; ++j) acc[j] = av[c0 + j] * acc[j] + si * bvv[c0 + j];
    }
    storef<VW>(out + (size_t)i * F + c0, acc);
}

// ---------- BN ----------
#define SROWS 128
template <int VW>
__global__ __launch_bounds__(256) void k_stats(const u16* __restrict__ h, float* __restrict__ s1,
                                               float* __restrict__ s2, int F) {
    int c0 = (blockIdx.x * 256 + threadIdx.x) * VW;
    int r0 = blockIdx.y * SROWS;
    float s[VW], q[VW];
    #pragma unroll
    for (int j = 0; j < VW; ++j) { s[j] = 0.f; q[j] = 0.f; }
    for (int r = r0; r < r0 + SROWS; ++r) {
        float v[VW];
        loadf<VW>(h + (size_t)r * F + c0, v);
        #pragma unroll
        for (int j = 0; j < VW; ++j) { s[j] += v[j]; q[j] += v[j] * v[j]; }
    }
    #pragma unroll
    for (int j = 0; j < VW; ++j) {
        atomicAdd(&s1[c0 + j], s[j]);
        atomicAdd(&s2[c0 + j], q[j]);
    }
}
__global__ void k_bnab(const float* __restrict__ s1, const float* __restrict__ s2,
                       const float* __restrict__ g, const float* __restrict__ be,
                       float* __restrict__ a, float* __restrict__ b, int F) {
    int c = blockIdx.x * 256 + threadIdx.x;
    if (c >= F) return;
    float m = s1[c] * (1.f / NN);
    float v = s2[c] * (1.f / NN) - m * m;
    float aa = g[c] * rsqrtf(v + 1e-5f);
    a[c] = aa;
    b[c] = be[c] - m * aa;
}
// fused stats->affine apply (a,b computed per-thread; VALU-cheap vs memory)
__global__ __launch_bounds__(256) void k_bnapply(u16* __restrict__ h, const float* __restrict__ s1,
                                                 const float* __restrict__ s2,
                                                 const float* __restrict__ g,
                                                 const float* __restrict__ be, int F) {
    size_t idx = blockIdx.x * (size_t)256 + threadIdx.x;
    int Fv = F >> 3;
    int c = (int)(idx % Fv) * 8;
    u16* p = h + idx * 8;
    float v[8];
    loadf<8>(p, v);
    #pragma unroll
    for (int j = 0; j < 8; ++j) {
        float m = s1[c + j] * (1.f / NN);
        float var = s2[c + j] * (1.f / NN) - m * m;
        float a = g[c + j] * rsqrtf(var + 1e-5f);
        v[j] = a * (v[j] - m) + be[c + j];
    }
    storef<8>(p, v);
}

// ================= 256x256 8-phase MFMA GEMM (f16) =================
// C[M,N] = A[M,K] @ Wt[N,K]^T. 512 thr = 8 waves (2 Mx4 N), BK=64,
// LDS 128 KiB: A[2buf][2Khalf][16KiB] @0, B same @64KiB.
// Granule perm byte(r,c)=r*64+((c^(r&3))<<4) -> conflict-free ds_read_b128;
// global source pre-permuted so LDS dest stays linear (gload_lds constraint).
// R6-measured schedule: q0 stages h1(kt+1) (A+B), q2 A-h0(kt+2), q3 B-h0(kt+2)
// + single vmcnt(4) at q3 end (never 0 in main loop).
__device__ __forceinline__ void stage16k(const char* gbase, size_t rs, int ktile, int h,
                                         char* slot, int tid) {
    size_t colb = (size_t)ktile * 128 + h * 64;
    #pragma unroll
    for (int i = 0; i < 2; ++i) {
        int G = i * 512 + tid;
        int r = G >> 2;
        int c = (G & 3) ^ (r & 3);
        __builtin_amdgcn_global_load_lds(AS1(gbase + (size_t)r * rs + colb + c * 16),
                                         AS3(slot + i * 8192 + ((tid >> 6) << 10)), 16, 0, 0);
    }
}

__global__ __launch_bounds__(512, 2) void k_gemm256(const u16* __restrict__ A,
                                                    const u16* __restrict__ Wt,
                                                    const float* __restrict__ bias,
                                                    u16* __restrict__ C,
                                                    int K, int N, int bx, int fuse) {
    extern __shared__ __align__(16) char smem[];
    int nwg = gridDim.x;
    int chunk = nwg >> 3;
    int swz = (blockIdx.x & 7) * chunk + (blockIdx.x >> 3);
    int tx = swz % bx, ty = swz / bx;
    int tid = threadIdx.x;
    int wid = tid >> 6, lane = tid & 63;
    int wr = wid >> 2, wc = wid & 3;         // 2 x 4 wave grid
    int lo = lane & 15, hi = lane >> 4;
    int sw = ((hi ^ (lo & 3)) << 4);
    size_t row0 = (size_t)ty * 256;
    size_t col0 = (size_t)tx * 256;
    int nkt = K >> 6;

    const char* gA = (const char*)(A + row0 * K);
    const char* gB = (const char*)(Wt + col0 * K);
    size_t rs = (size_t)K * 2;

    const char* aA = smem + wr * 8192 + lo * 64 + sw;           // + buf*32768 + kk*16384 + mh*4096 + j*1024
    const char* bA = smem + 65536 + wc * 4096 + lo * 64 + sw;   // + buf*32768 + kk*16384 + j*1024
#define ASL(b, h) (smem + (((b) * 2 + (h)) << 14))
#define BSL(b, h) (smem + 65536 + (((b) * 2 + (h)) << 14))

    f32x4 acc[8][4];
    #pragma unroll
    for (int m = 0; m < 8; ++m)
        #pragma unroll
        for (int n = 0; n < 4; ++n) acc[m][n] = {0.f, 0.f, 0.f, 0.f};
    half8 af[4], bf[4];

    // ---- prologue: kt0 fully + kt1 h0 ----
    stage16k(gA, rs, 0, 0, ASL(0, 0), tid);
    stage16k(gB, rs, 0, 0, BSL(0, 0), tid);
    stage16k(gA, rs, 0, 1, ASL(0, 1), tid);
    stage16k(gB, rs, 0, 1, BSL(0, 1), tid);
    stage16k(gA, rs, 1, 0, ASL(1, 0), tid);
    stage16k(gB, rs, 1, 0, BSL(1, 0), tid);
    asm volatile("s_waitcnt vmcnt(4)" ::: "memory");
    __builtin_amdgcn_sched_barrier(0);
    __builtin_amdgcn_s_barrier();

#define DS_LOADS(KK, MH)                                                                   \
    {                                                                                      \
        _Pragma("unroll") for (int j = 0; j < 4; ++j)                                      \
            af[j] = *(const half8*)(aA + buf * 32768 + (KK) * 16384 + (MH) * 4096 + j * 1024); \
        if ((MH) == 0) {                                                                   \
            _Pragma("unroll") for (int j = 0; j < 4; ++j)                                  \
                bf[j] = *(const half8*)(bA + buf * 32768 + (KK) * 16384 + j * 1024);       \
        }                                                                                  \
    }
#define MFMA_PHASE(MH)                                                                     \
    {                                                                                      \
        asm volatile("" ::: "memory");                                                     \
        __builtin_amdgcn_s_barrier();                                                      \
        __builtin_amdgcn_s_setprio(1);                                                     \
        _Pragma("unroll") for (int j = 0; j < 4; ++j)                                      \
            _Pragma("unroll") for (int n = 0; n < 4; ++n)                                  \
                acc[(MH) * 4 + j][n] = __builtin_amdgcn_mfma_f32_16x16x32_f16(             \
                    af[j], bf[n], acc[(MH) * 4 + j][n], 0, 0, 0);                          \
        __builtin_amdgcn_s_setprio(0);                                                     \
    }
#define END_BARRIER                                                                        \
    {                                                                                      \
        asm volatile("" ::: "memory");                                                     \
        __builtin_amdgcn_s_barrier();                                                      \
    }

    for (int kt = 0; kt < nkt; ++kt) {
        int buf = kt & 1;
        // q0: kk=0, fm 0-3 ; stage h1(kt+1) into buf^1
        DS_LOADS(0, 0);
        if (kt + 1 < nkt) {
            stage16k(gA, rs, kt + 1, 1, ASL(buf ^ 1, 1), tid);
            stage16k(gB, rs, kt + 1, 1, BSL(buf ^ 1, 1), tid);
        }
        MFMA_PHASE(0);
        END_BARRIER;
        // q1: kk=0, fm 4-7 (bf reused)
        DS_LOADS(0, 1);
        MFMA_PHASE(1);
        END_BARRIER;
        // q2: kk=1, fm 0-3 ; stage A-h0(kt+2) into buf
        DS_LOADS(1, 0);
        if (kt + 2 < nkt) stage16k(gA, rs, kt + 2, 0, ASL(buf, 0), tid);
        MFMA_PHASE(0);
        END_BARRIER;
        // q3: kk=1, fm 4-7 ; stage B-h0(kt+2) ; K-tile boundary: counted vmcnt
        DS_LOADS(1, 1);
        if (kt + 2 < nkt) stage16k(gB, rs, kt + 2, 0, BSL(buf, 0), tid);
        MFMA_PHASE(1);
        asm volatile("s_waitcnt vmcnt(4)" ::: "memory");
        __builtin_amdgcn_sched_barrier(0);
        END_BARRIER;
    }

    // ---- epilogue ----
    #pragma unroll
    for (int fm = 0; fm < 8; ++fm) {
        #pragma unroll
        for (int n = 0; n < 4; ++n) {
            #pragma unroll
            for (int r = 0; r < 4; ++r) {
                size_t row = row0 + wr * 128 + fm * 16 + hi * 4 + r;
                size_t col = col0 + wc * 64 + n * 16 + lo;
                float v = acc[fm][n][r];
                if (fuse) v = fmaxf(v + bias[col], 0.f);
                C[row * N + col] = f2b(v);
            }
        }
    }
#undef DS_LOADS
#undef MFMA_PHASE
#undef END_BARRIER
#undef ASL
#undef BSL
}

// ---------- 128x128 m97-style GEMM (kept for N=256 layer) ----------
__global__ __launch_bounds__(256) void k_gemm(const u16* __restrict__ A, const u16* __restrict__ Wt,
                                              const float* __restrict__ bias, u16* __restrict__ C,
                                              int K, int N, int bx, int fuse) {
    __shared__ __align__(16) u16 As[128 * 32];
    __shared__ __align__(16) u16 Bs[128 * 32];
    int nwg = gridDim.x;
    int chunk = nwg >> 3;
    int swz = (blockIdx.x & 7) * chunk + (blockIdx.x >> 3);
    int tx = swz % bx, ty = swz / bx;
    int tid = threadIdx.x;
    int wid = tid >> 6, lane = tid & 63;
    int wr = wid >> 1, wc = wid & 1;
    int lo = lane & 15, hi = lane >> 4;
    size_t row0 = (size_t)ty * 128;
    size_t col0 = (size_t)tx * 128;

    f32x4 acc[4][4];
    #pragma unroll
    for (int m = 0; m < 4; ++m)
        #pragma unroll
        for (int n = 0; n < 4; ++n) acc[m][n] = {0.f, 0.f, 0.f, 0.f};

    const char* gA = (const char*)(A + row0 * K);
    const char* gB = (const char*)(Wt + col0 * K);
    size_t rs = (size_t)K * 2;
    int lin0 = tid * 16;
    int lin1 = lin0 + 4096;
    int rA0 = lin0 >> 6, cb0 = lin0 & 63;
    int rA1 = lin1 >> 6, cb1 = lin1 & 63;
    unsigned ldsOff = (unsigned)(wid << 10);

    for (int k0 = 0; k0 < K; k0 += 32) {
        __syncthreads();
        size_t kb = (size_t)k0 * 2;
        __builtin_amdgcn_global_load_lds(AS1(gA + (size_t)rA0 * rs + cb0 + kb),
                                         AS3((char*)As + ldsOff), 16, 0, 0);
        __builtin_amdgcn_global_load_lds(AS1(gA + (size_t)rA1 * rs + cb1 + kb),
                                         AS3((char*)As + 4096 + ldsOff), 16, 0, 0);
        __builtin_amdgcn_global_load_lds(AS1(gB + (size_t)rA0 * rs + cb0 + kb),
                                         AS3((char*)Bs + ldsOff), 16, 0, 0);
        __builtin_amdgcn_global_load_lds(AS1(gB + (size_t)rA1 * rs + cb1 + kb),
                                         AS3((char*)Bs + 4096 + ldsOff), 16, 0, 0);
        __syncthreads();
        half8 afr[4], bfr[4];
        #pragma unroll
        for (int m = 0; m < 4; ++m)
            afr[m] = *(const half8*)((const u16*)As + (wr * 64 + m * 16 + lo) * 32 + hi * 8);
        #pragma unroll
        for (int n = 0; n < 4; ++n)
            bfr[n] = *(const half8*)((const u16*)Bs + (wc * 64 + n * 16 + lo) * 32 + hi * 8);
        #pragma unroll
        for (int m = 0; m < 4; ++m)
            #pragma unroll
            for (int n = 0; n < 4; ++n)
                acc[m][n] = __builtin_amdgcn_mfma_f32_16x16x32_f16(afr[m], bfr[n], acc[m][n], 0, 0, 0);
    }
    #pragma unroll
    for (int m = 0; m < 4; ++m) {
        #pragma unroll
        for (int n = 0; n < 4; ++n) {
            #pragma unroll
            for (int r = 0; r < 4; ++r) {
                size_t row = row0 + wr * 64 + m * 16 + hi * 4 + r;
                size_t col = col0 + wc * 64 + n * 16 + lo;
                float v = acc[m][n][r];
                if (fuse) v = fmaxf(v + bias[col], 0.f);
                C[row * N + col] = f2b(v);
            }
        }
    }
}

// ---------- layer 7: fused BN6 + GEMV ----------
__global__ __launch_bounds__(256) void k_gemv(const u16* __restrict__ A, const float* __restrict__ w,
                                              const float* __restrict__ a, const float* __restrict__ b,
                                              float* __restrict__ y) {
    int row = blockIdx.x * 4 + (threadIdx.x >> 6);
    int lane = threadIdx.x & 63;
    const u16* h = A + (size_t)row * 256;
    float s = 0.f;
    #pragma unroll
    for (int j = 0; j < 4; ++j) {
        int c = lane + j * 64;
        s += (a[c] * b2f(h[c]) + b[c]) * w[c];
    }
    #pragma unroll
    for (int off = 32; off; off >>= 1) s += __shfl_down(s, off);
    if (lane == 0) y[row] = s;
}
__global__ void k_final(const float* __restrict__ y, const int* __restrict__ rowptr,
                        const int* __restrict__ csr_src, const float* __restrict__ csr_w,
                        const float* __restrict__ dinv, const int* __restrict__ batch,
                        const float* __restrict__ b7, float* __restrict__ out) {
    int i = blockIdx.x * 256 + threadIdx.x;
    if (i >= NN) return;
    float v = dinv[i] * dinv[i] * y[i];
    int r1 = rowptr[i + 1];
    for (int e = rowptr[i]; e < r1; ++e) v += csr_w[e] * y[csr_src[e]];
    atomicAdd(&out[batch[i]], v + b7[0]);
}
__global__ void k_sentinel(float* out, float v) {
    if (threadIdx.x == 0 && blockIdx.x == 0) out[0] = v;
}

// ---------- host ----------
static inline char* alignp(char* p) { return (char*)(((uintptr_t)p + 255) & ~(uintptr_t)255); }

extern "C" void kernel_launch(void* const* d_in, const int* in_sizes, int n_in,
                              void* d_out, int out_size, void* d_ws, size_t ws_size,
                              hipStream_t stream) {
    const float* x = (const float*)d_in[0];
    const int* ei = (const int*)d_in[1];
    const int* src = ei;
    const int* dst = ei + NE;
    const int* batch = (const int*)d_in[2];
    const float* W[7]; const float* bv[7];
    for (int i = 0; i < 7; ++i) { W[i] = (const float*)d_in[3 + 2 * i]; bv[i] = (const float*)d_in[4 + 2 * i]; }
    const float* g[6]; const float* be[6];
    for (int i = 0; i < 6; ++i) { g[i] = (const float*)d_in[17 + 2 * i]; be[i] = (const float*)d_in[18 + 2 * i]; }
    float* out = (float*)d_out;

    // workspace layout
    char* p = (char*)d_ws;
    u16* Abuf = (u16*)p; p += (size_t)NN * 4096 * 2;
    u16* Bbuf = (u16*)p; p += (size_t)NN * 2048 * 2;
    u16* xpad = (u16*)p; p += (size_t)NN * 512 * 2;
    u16* W1t = (u16*)p; p += (size_t)4096 * 512 * 2;
    u16* W2t = (u16*)p; p += (size_t)2048 * 4096 * 2;
    u16* W3t = (u16*)p; p += (size_t)1024 * 2048 * 2;
    u16* W4t = (u16*)p; p += (size_t)1024 * 1024 * 2;
    u16* W5t = (u16*)p; p += (size_t)2048 * 1024 * 2;
    u16* W6t = (u16*)p; p += (size_t)256 * 2048 * 2;
    p = alignp(p);
    int* degi = (int*)p; p += NN * 4;
    int* cursor = (int*)p; p += NN * 4;
    int* rowptr = (int*)p; p += (NN + 1) * 4; p = alignp(p);
    int* csr_src = (int*)p; p += NE * 4;
    float* csr_w = (float*)p; p += NE * 4;
    float* dinv = (float*)p; p += NN * 4;
    float* nrm = (float*)p; p += NE * 4;
    float* svec = (float*)p; p += NN * 4;
    float* s1 = (float*)p; p += 4096 * 4;
    float* s2 = (float*)p; p += 4096 * 4;
    float* bna = (float*)p; p += 4096 * 4;
    float* bnb = (float*)p; p += 4096 * 4;
    float* y = (float*)p; p += NN * 4;
    size_t need = (size_t)(p - (char*)d_ws);
    if (need > ws_size) {
        hipMemsetAsync(d_out, 0, NG * sizeof(float), stream);
        k_sentinel<<<1, 64, 0, stream>>>(out, (float)(ws_size >> 20));
        return;
    }

    (void)hipFuncSetAttribute((const void*)k_gemm256,
                              hipFuncAttributeMaxDynamicSharedMemorySize, 131072);

    // --- graph prep ---
    hipMemsetAsync(degi, 0, 2 * NN * sizeof(int), stream);  // degi + cursor
    k_degi<<<NE / 256, 256, 0, stream>>>(dst, degi);
    k_dinv<<<NN / 256, 256, 0, stream>>>(degi, dinv);
    k_nrm<<<NE / 256, 256, 0, stream>>>(src, dst, dinv, nrm);
    k_scan<<<1, 1024, 0, stream>>>(degi, rowptr);
    k_place<<<NE / 256, 256, 0, stream>>>(src, dst, nrm, rowptr, cursor, csr_src, csr_w);
    k_srow<<<NN / 256, 256, 0, stream>>>(rowptr, csr_w, dinv, svec);

    // --- upfront conversions ---
    k_x2b<<<(NN * 512) / 256, 256, 0, stream>>>(x, xpad);
    {
        dim3 b(32, 8);
        k_wt<<<dim3(16, 128), b, 0, stream>>>(W[0], W1t, 396, 512, 4096);
        k_wt<<<dim3(128, 64), b, 0, stream>>>(W[1], W2t, 4096, 4096, 2048);
        k_wt<<<dim3(64, 32), b, 0, stream>>>(W[2], W3t, 2048, 2048, 1024);
        k_wt<<<dim3(32, 32), b, 0, stream>>>(W[3], W4t, 1024, 1024, 1024);
        k_wt<<<dim3(32, 64), b, 0, stream>>>(W[4], W5t, 1024, 1024, 2048);
        k_wt<<<dim3(64, 8), b, 0, stream>>>(W[5], W6t, 2048, 2048, 256);
    }

    auto gemm = [&](const u16* A, const u16* Wt, const float* bias, u16* Cp, int K, int N, int fuse) {
        if (N >= 1024) {
            int bx = N / 256;
            k_gemm256<<<bx * (NN / 256), 512, 131072, stream>>>(A, Wt, bias, Cp, K, N, bx, fuse);
        } else {
            int bx = N / 128;
            k_gemm<<<bx * (NN / 128), 256, 0, stream>>>(A, Wt, bias, Cp, K, N, bx, fuse);
        }
    };
    auto agg = [&](const u16* in, u16* o, const float* bias, const float* av,
                   const float* bvv, int F, int mode) {
        if (F == 2048) k_agg<8><<<NN, 256, 0, stream>>>(in, o, rowptr, csr_src, csr_w, dinv, svec, bias, av, bvv, F, mode);
        else if (F == 1024) k_agg<4><<<NN, 256, 0, stream>>>(in, o, rowptr, csr_src, csr_w, dinv, svec, bias, av, bvv, F, mode);
        else if (F == 512) k_agg<2><<<NN, 256, 0, stream>>>(in, o, rowptr, csr_src, csr_w, dinv, svec, bias, av, bvv, F, mode);
        else k_agg<1><<<NN, 256, 0, stream>>>(in, o, rowptr, csr_src, csr_w, dinv, svec, bias, av, bvv, F, mode);
    };
    auto stats = [&](const u16* h, int F) {
        hipMemsetAsync(s1, 0, 2 * 4096 * sizeof(float), stream);   // s1+s2
        if (F == 4096) k_stats<8><<<dim3(2, NN / SROWS), 256, 0, stream>>>(h, s1, s2, F);
        else if (F == 2048) k_stats<8><<<dim3(1, NN / SROWS), 256, 0, stream>>>(h, s1, s2, F);
        else if (F == 1024) k_stats<4><<<dim3(1, NN / SROWS), 256, 0, stream>>>(h, s1, s2, F);
        else k_stats<1><<<dim3(1, NN / SROWS), 256, 0, stream>>>(h, s1, s2, F);
    };
    auto bnapply = [&](u16* h, int F, int li) {
        k_bnapply<<<(int)(((size_t)NN * F / 8) / 256), 256, 0, stream>>>(h, s1, s2, g[li], be[li], F);
    };

    // --- L1: 396(512) -> 4096, agg-first; BN1 applied (fused stats->apply) ---
    agg(xpad, Bbuf, nullptr, nullptr, nullptr, 512, 0);
    gemm(Bbuf, W1t, bv[0], Abuf, 512, 4096, 1);
    stats(Abuf, 4096);
    bnapply(Abuf, 4096, 0);

    // --- L2: 4096 -> 2048, gemm-first; BN2 applied ---
    gemm(Abuf, W2t, nullptr, Bbuf, 4096, 2048, 0);
    agg(Bbuf, Abuf, bv[1], nullptr, nullptr, 2048, 1);
    stats(Abuf, 2048);
    bnapply(Abuf, 2048, 1);

    // --- L3: 2048 -> 1024, gemm-first; BN3 applied ---
    gemm(Abuf, W3t, nullptr, Bbuf, 2048, 1024, 0);
    agg(Bbuf, Abuf, bv[2], nullptr, nullptr, 1024, 1);
    stats(Abuf, 1024);
    bnapply(Abuf, 1024, 2);

    // --- L4: 1024 -> 1024, gemm-first; BN4 left unapplied (folded into L5 agg) ---
    gemm(Abuf, W4t, nullptr, Bbuf, 1024, 1024, 0);
    agg(Bbuf, Abuf, bv[3], nullptr, nullptr, 1024, 1);
    stats(Abuf, 1024);
    k_bnab<<<1024 / 256, 256, 0, stream>>>(s1, s2, g[3], be[3], bna, bnb, 1024);

    // --- L5: 1024 -> 2048, agg-first with BN4 fold ---
    agg(Abuf, Bbuf, nullptr, bna, bnb, 1024, 2);
    gemm(Bbuf, W5t, bv[4], Abuf, 1024, 2048, 1);
    stats(Abuf, 2048);
    bnapply(Abuf, 2048, 4);

    // --- L6: 2048 -> 256, gemm-first (128^2 kernel); BN6 folded into GEMV ---
    gemm(Abuf, W6t, nullptr, Bbuf, 2048, 256, 0);
    agg(Bbuf, Abuf, bv[5], nullptr, nullptr, 256, 1);
    stats(Abuf, 256);
    k_bnab<<<1, 256, 0, stream>>>(s1, s2, g[5], be[5], bna, bnb, 256);

    // --- L7: 256 -> 1 with BN6 fused in GEMV, then agg + pool ---
    k_gemv<<<NN / 4, 256, 0, stream>>>(Abuf, W[6], bna, bnb, y);
    hipMemsetAsync(d_out, 0, NG * sizeof(float), stream);
    k_final<<<NN / 256, 256, 0, stream>>>(y, rowptr, csr_src, csr_w, dinv, batch, bv[6], out);
}

// Round 9
// 1503.273 us; speedup vs baseline: 1.0049x; 1.0049x over previous
//
#include <hip/hip_runtime.h>

// GCN: 7x GCNConv (first 6 with ReLU+BN training-mode), then global_add_pool.
// N=16384 nodes, E=131072 edges, 64 graphs. fp32 in/out, fp16 internal + MFMA
// (f16 ulp 2^-11: absmax 0.125 vs 0.645 threshold, 5x margin).
// agg on the narrow side per layer (agg is linear). BN4->L5-agg and BN6->GEMV
// folds kept (fp32-register); other BN layers: fused stats->apply pass.
// GEMM: 256x256 8-phase schedule. R9: rotation swizzle cg=(c+(r>>1))&3 replaces
// XOR cg=c^(r&3) -- old perm left a systematic 2-way phase conflict (25M
// SQ_LDS_BANK_CONFLICT measured R8); rotation covers all 32 banks per 8-lane phase.

#define NN 16384
#define NE 131072
#define NG 64

typedef unsigned int u32;
typedef unsigned short u16;
typedef __attribute__((ext_vector_type(8))) _Float16 half8;
typedef __attribute__((ext_vector_type(4))) float f32x4;
typedef __attribute__((ext_vector_type(8))) u16 us8;
typedef __attribute__((ext_vector_type(4))) u16 us4;
typedef __attribute__((ext_vector_type(2))) u16 us2;

#define AS1(p) ((const __attribute__((address_space(1))) void*)(p))
#define AS3(p) ((__attribute__((address_space(3))) void*)(p))

// f16 <-> f32 (RNE on the way down)
__device__ __forceinline__ float b2f(u16 h) {
    _Float16 x = __builtin_bit_cast(_Float16, h);
    return (float)x;
}
__device__ __forceinline__ u16 f2b(float f) {
    _Float16 x = (_Float16)f;
    return __builtin_bit_cast(u16, x);
}

template <int VW> struct VecU;
template <> struct VecU<8> { typedef us8 T; };
template <> struct VecU<4> { typedef us4 T; };
template <> struct VecU<2> { typedef us2 T; };
template <> struct VecU<1> { typedef u16 T; };

template <int VW>
__device__ __forceinline__ void loadf(const u16* p, float* f) {
    typename VecU<VW>::T v = *(const typename VecU<VW>::T*)p;
    if constexpr (VW == 1) {
        f[0] = b2f((u16)v);
    } else {
        #pragma unroll
        for (int j = 0; j < VW; ++j) f[j] = b2f(v[j]);
    }
}
template <int VW>
__device__ __forceinline__ void storef(u16* p, const float* f) {
    typename VecU<VW>::T v;
    if constexpr (VW == 1) {
        v = f2b(f[0]);
    } else {
        #pragma unroll
        for (int j = 0; j < VW; ++j) v[j] = f2b(f[j]);
    }
    *(typename VecU<VW>::T*)p = v;
}

// ---------- graph prep ----------
__global__ void k_degi(const int* __restrict__ dst, int* __restrict__ deg) {
    int e = blockIdx.x * 256 + threadIdx.x;
    if (e < NE) atomicAdd(&deg[dst[e]], 1);
}
__global__ void k_dinv(const int* __restrict__ deg, float* __restrict__ dinv) {
    int i = blockIdx.x * 256 + threadIdx.x;
    if (i < NN) dinv[i] = rsqrtf((float)(deg[i] + 1));   // +1 self loop
}
__global__ void k_nrm(const int* __restrict__ src, const int* __restrict__ dst,
                      const float* __restrict__ dinv, float* __restrict__ nrm) {
    int e = blockIdx.x * 256 + threadIdx.x;
    if (e < NE) nrm[e] = dinv[src[e]] * dinv[dst[e]];
}
__global__ __launch_bounds__(1024) void k_scan(const int* __restrict__ deg, int* __restrict__ rowptr) {
    __shared__ int part[1024];
    int t = threadIdx.x;
    int base = t * 16;
    int s = 0;
    #pragma unroll
    for (int j = 0; j < 16; ++j) s += deg[base + j];
    part[t] = s;
    __syncthreads();
    for (int off = 1; off < 1024; off <<= 1) {
        int v = 0;
        if (t >= off) v = part[t - off];
        __syncthreads();
        part[t] += v;
        __syncthreads();
    }
    int run = part[t] - s;  // exclusive prefix
    for (int j = 0; j < 16; ++j) { rowptr[base + j] = run; run += deg[base + j]; }
    if (t == 1023) rowptr[NN] = run;
}
__global__ void k_place(const int* __restrict__ src, const int* __restrict__ dst,
                        const float* __restrict__ nrm, const int* __restrict__ rowptr,
                        int* __restrict__ cursor, int* __restrict__ csr_src,
                        float* __restrict__ csr_w) {
    int e = blockIdx.x * 256 + threadIdx.x;
    if (e >= NE) return;
    int d = dst[e];
    int p = rowptr[d] + atomicAdd(&cursor[d], 1);
    csr_src[p] = src[e];
    csr_w[p] = nrm[e];
}
// s_i = dinv_i^2 + sum of edge weights into i
__global__ void k_srow(const int* __restrict__ rowptr, const float* __restrict__ csr_w,
                       const float* __restrict__ dinv, float* __restrict__ svec) {
    int i = blockIdx.x * 256 + threadIdx.x;
    if (i >= NN) return;
    float s = dinv[i] * dinv[i];
    int r1 = rowptr[i + 1];
    for (int e = rowptr[i]; e < r1; ++e) s += csr_w[e];
    svec[i] = s;
}

// ---------- conversions ----------
__global__ void k_x2b(const float* __restrict__ x, u16* __restrict__ xp) {
    int idx = blockIdx.x * 256 + threadIdx.x;   // over NN*512
    int i = idx >> 9, c = idx & 511;
    float v = (c < 396) ? x[(size_t)i * 396 + c] : 0.f;
    xp[idx] = f2b(v);
}
// Wt[n][k] = f16(W[k][n]), K padded with zeros
__global__ void k_wt(const float* __restrict__ W, u16* __restrict__ Wt,
                     int Ksrc, int Kpad, int N) {
    __shared__ float t[32][33];
    int k0 = blockIdx.x * 32, n0 = blockIdx.y * 32;
    #pragma unroll
    for (int j = 0; j < 4; ++j) {
        int k = k0 + threadIdx.y + j * 8;
        float v = 0.f;
        if (k < Ksrc) v = W[(size_t)k * N + n0 + threadIdx.x];
        t[threadIdx.y + j * 8][threadIdx.x] = v;
    }
    __syncthreads();
    #pragma unroll
    for (int j = 0; j < 4; ++j) {
        int n = n0 + threadIdx.y + j * 8;
        int k = k0 + threadIdx.x;
        Wt[(size_t)n * Kpad + k] = f2b(t[threadIdx.x][threadIdx.y + j * 8]);
    }
}

// ---------- CSR gather aggregation (one block per node) ----------
// mode 0: out = acc ; mode 1: out = relu(acc + bias) ; mode 2: out = av*acc + s_i*bvv
template <int VW>
__global__ __launch_bounds__(256) void k_agg(const u16* __restrict__ in, u16* __restrict__ out,
                                             const int* __restrict__ rowptr,
                                             const int* __restrict__ csr_src,
                                             const float* __restrict__ csr_w,
                                             const float* __restrict__ dinv,
                                             const float* __restrict__ svec,
                                             const float* __restrict__ bias,
                                             const float* __restrict__ av,
                                             const float* __restrict__ bvv,
                                             int F, int mode) {
    int i = blockIdx.x;
    int c0 = threadIdx.x * VW;
    float acc[VW];
    float d2 = dinv[i]; d2 *= d2;
    {
        float v[VW];
        loadf<VW>(in + (size_t)i * F + c0, v);
        #pragma unroll
        for (int j = 0; j < VW; ++j) acc[j] = d2 * v[j];
    }
    int r0 = rowptr[i], r1 = rowptr[i + 1];
    for (int e = r0; e < r1; ++e) {
        int s = csr_src[e];
        float w = csr_w[e];
        float v[VW];
        loadf<VW>(in + (size_t)s * F + c0, v);
        #pragma unroll
        for (int j = 0; j < VW; ++j) acc[j] += w * v[j];
    }
    if (mode == 1) {
        #pragma unroll
        for (int j = 0; j < VW; ++j) acc[j] = fmaxf(acc[j] + bias[c0 + j], 0.f);
    } else if (mode == 2) {
        float si = svec[i];
        #pragma unroll
        for (int j = 0; j < VW; ++j) acc[j] = av[c0 + j] * acc[j] + si * bvv[c0 + j];
    }
    storef<VW>(out + (size_t)i * F + c0, acc);
}

// ---------- BN ----------
#define SROWS 128
template <int VW>
__global__ __launch_bounds__(256) void k_stats(const u16* __restrict__ h, float* __restrict__ s1,
                                               float* __restrict__ s2, int F) {
    int c0 = (blockIdx.x * 256 + threadIdx.x) * VW;
    int r0 = blockIdx.y * SROWS;
    float s[VW], q[VW];
    #pragma unroll
    for (int j = 0; j < VW; ++j) { s[j] = 0.f; q[j] = 0.f; }
    for (int r = r0; r < r0 + SROWS; ++r) {
        float v[VW];
        loadf<VW>(h + (size_t)r * F + c0, v);
        #pragma unroll
        for (int j = 0; j < VW; ++j) { s[j] += v[j]; q[j] += v[j] * v[j]; }
    }
    #pragma unroll
    for (int j = 0; j < VW; ++j) {
        atomicAdd(&s1[c0 + j], s[j]);
        atomicAdd(&s2[c0 + j], q[j]);
    }
}
__global__ void k_bnab(const float* __restrict__ s1, const float* __restrict__ s2,
                       const float* __restrict__ g, const float* __restrict__ be,
                       float* __restrict__ a, float* __restrict__ b, int F) {
    int c = blockIdx.x * 256 + threadIdx.x;
    if (c >= F) return;
    float m = s1[c] * (1.f / NN);
    float v = s2[c] * (1.f / NN) - m * m;
    float aa = g[c] * rsqrtf(v + 1e-5f);
    a[c] = aa;
    b[c] = be[c] - m * aa;
}
// fused stats->affine apply (a,b computed per-thread; VALU-cheap vs memory)
__global__ __launch_bounds__(256) void k_bnapply(u16* __restrict__ h, const float* __restrict__ s1,
                                                 const float* __restrict__ s2,
                                                 const float* __restrict__ g,
                                                 const float* __restrict__ be, int F) {
    size_t idx = blockIdx.x * (size_t)256 + threadIdx.x;
    int Fv = F >> 3;
    int c = (int)(idx % Fv) * 8;
    u16* p = h + idx * 8;
    float v[8];
    loadf<8>(p, v);
    #pragma unroll
    for (int j = 0; j < 8; ++j) {
        float m = s1[c + j] * (1.f / NN);
        float var = s2[c + j] * (1.f / NN) - m * m;
        float a = g[c + j] * rsqrtf(var + 1e-5f);
        v[j] = a * (v[j] - m) + be[c + j];
    }
    storef<8>(p, v);
}

// ================= 256x256 8-phase MFMA GEMM (f16) =================
// C[M,N] = A[M,K] @ Wt[N,K]^T. 512 thr = 8 waves (2 Mx4 N), BK=64,
// LDS 128 KiB: A[2buf][2Khalf][16KiB] @0, B same @64KiB.
// Rotation perm: global granule c of row r stored at LDS granule (c+(r>>1))&3
// (dest linear for gload_lds; source pre-permuted). Read lane (hi,lo) fetches
// LDS granule (hi+(lo>>1))&3 -> data granule hi; 8-lane phase covers all 32
// banks exactly once (parity x 4 rotations) -> conflict-free ds_read_b128.
// Schedule: q0 stages h1(kt+1) (A+B), q2 A-h0(kt+2), q3 B-h0(kt+2)
// + single vmcnt(4) at q3 end (never 0 in main loop).
__device__ __forceinline__ void stage16k(const char* gbase, size_t rs, int ktile, int h,
                                         char* slot, int tid) {
    size_t colb = (size_t)ktile * 128 + h * 64;
    #pragma unroll
    for (int i = 0; i < 2; ++i) {
        int G = i * 512 + tid;
        int r = G >> 2;
        int c = ((G & 3) - (r >> 1)) & 3;   // inverse of storage rotation
        __builtin_amdgcn_global_load_lds(AS1(gbase + (size_t)r * rs + colb + c * 16),
                                         AS3(slot + i * 8192 + ((tid >> 6) << 10)), 16, 0, 0);
    }
}

__global__ __launch_bounds__(512, 2) void k_gemm256(const u16* __restrict__ A,
                                                    const u16* __restrict__ Wt,
                                                    const float* __restrict__ bias,
                                                    u16* __restrict__ C,
                                                    int K, int N, int bx, int fuse) {
    extern __shared__ __align__(16) char smem[];
    int nwg = gridDim.x;
    int chunk = nwg >> 3;
    int swz = (blockIdx.x & 7) * chunk + (blockIdx.x >> 3);
    int tx = swz % bx, ty = swz / bx;
    int tid = threadIdx.x;
    int wid = tid >> 6, lane = tid & 63;
    int wr = wid >> 2, wc = wid & 3;         // 2 x 4 wave grid
    int lo = lane & 15, hi = lane >> 4;
    int sw = (((hi + (lo >> 1)) & 3) << 4);  // rotation swizzle (conflict-free)
    size_t row0 = (size_t)ty * 256;
    size_t col0 = (size_t)tx * 256;
    int nkt = K >> 6;

    const char* gA = (const char*)(A + row0 * K);
    const char* gB = (const char*)(Wt + col0 * K);
    size_t rs = (size_t)K * 2;

    const char* aA = smem + wr * 8192 + lo * 64 + sw;           // + buf*32768 + kk*16384 + mh*4096 + j*1024
    const char* bA = smem + 65536 + wc * 4096 + lo * 64 + sw;   // + buf*32768 + kk*16384 + j*1024
#define ASL(b, h) (smem + (((b) * 2 + (h)) << 14))
#define BSL(b, h) (smem + 65536 + (((b) * 2 + (h)) << 14))

    f32x4 acc[8][4];
    #pragma unroll
    for (int m = 0; m < 8; ++m)
        #pragma unroll
        for (int n = 0; n < 4; ++n) acc[m][n] = {0.f, 0.f, 0.f, 0.f};
    half8 af[4], bf[4];

    // ---- prologue: kt0 fully + kt1 h0 ----
    stage16k(gA, rs, 0, 0, ASL(0, 0), tid);
    stage16k(gB, rs, 0, 0, BSL(0, 0), tid);
    stage16k(gA, rs, 0, 1, ASL(0, 1), tid);
    stage16k(gB, rs, 0, 1, BSL(0, 1), tid);
    stage16k(gA, rs, 1, 0, ASL(1, 0), tid);
    stage16k(gB, rs, 1, 0, BSL(1, 0), tid);
    asm volatile("s_waitcnt vmcnt(4)" ::: "memory");
    __builtin_amdgcn_sched_barrier(0);
    __builtin_amdgcn_s_barrier();

#define DS_LOADS(KK, MH)                                                                   \
    {                                                                                      \
        _Pragma("unroll") for (int j = 0; j < 4; ++j)                                      \
            af[j] = *(const half8*)(aA + buf * 32768 + (KK) * 16384 + (MH) * 4096 + j * 1024); \
        if ((MH) == 0) {                                                                   \
            _Pragma("unroll") for (int j = 0; j < 4; ++j)                                  \
                bf[j] = *(const half8*)(bA + buf * 32768 + (KK) * 16384 + j * 1024);       \
        }                                                                                  \
    }
#define MFMA_PHASE(MH)                                                                     \
    {                                                                                      \
        asm volatile("" ::: "memory");                                                     \
        __builtin_amdgcn_s_barrier();                                                      \
        __builtin_amdgcn_s_setprio(1);                                                     \
        _Pragma("unroll") for (int j = 0; j < 4; ++j)                                      \
            _Pragma("unroll") for (int n = 0; n < 4; ++n)                                  \
                acc[(MH) * 4 + j][n] = __builtin_amdgcn_mfma_f32_16x16x32_f16(             \
                    af[j], bf[n], acc[(MH) * 4 + j][n], 0, 0, 0);                          \
        __builtin_amdgcn_s_setprio(0);                                                     \
    }
#define END_BARRIER                                                                        \
    {                                                                                      \
        asm volatile("" ::: "memory");                                                     \
        __builtin_amdgcn_s_barrier();                                                      \
    }

    for (int kt = 0; kt < nkt; ++kt) {
        int buf = kt & 1;
        // q0: kk=0, fm 0-3 ; stage h1(kt+1) into buf^1
        DS_LOADS(0, 0);
        if (kt + 1 < nkt) {
            stage16k(gA, rs, kt + 1, 1, ASL(buf ^ 1, 1), tid);
            stage16k(gB, rs, kt + 1, 1, BSL(buf ^ 1, 1), tid);
        }
        MFMA_PHASE(0);
        END_BARRIER;
        // q1: kk=0, fm 4-7 (bf reused)
        DS_LOADS(0, 1);
        MFMA_PHASE(1);
        END_BARRIER;
        // q2: kk=1, fm 0-3 ; stage A-h0(kt+2) into buf
        DS_LOADS(1, 0);
        if (kt + 2 < nkt) stage16k(gA, rs, kt + 2, 0, ASL(buf, 0), tid);
        MFMA_PHASE(0);
        END_BARRIER;
        // q3: kk=1, fm 4-7 ; stage B-h0(kt+2) ; K-tile boundary: counted vmcnt
        DS_LOADS(1, 1);
        if (kt + 2 < nkt) stage16k(gB, rs, kt + 2, 0, BSL(buf, 0), tid);
        MFMA_PHASE(1);
        asm volatile("s_waitcnt vmcnt(4)" ::: "memory");
        __builtin_amdgcn_sched_barrier(0);
        END_BARRIER;
    }

    // ---- epilogue ----
    #pragma unroll
    for (int fm = 0; fm < 8; ++fm) {
        #pragma unroll
        for (int n = 0; n < 4; ++n) {
            #pragma unroll
            for (int r = 0; r < 4; ++r) {
                size_t row = row0 + wr * 128 + fm * 16 + hi * 4 + r;
                size_t col = col0 + wc * 64 + n * 16 + lo;
                float v = acc[fm][n][r];
                if (fuse) v = fmaxf(v + bias[col], 0.f);
                C[row * N + col] = f2b(v);
            }
        }
    }
#undef DS_LOADS
#undef MFMA_PHASE
#undef END_BARRIER
#undef ASL
#undef BSL
}

// ---------- 128x128 m97-style GEMM (kept for N=256 layer) ----------
__global__ __launch_bounds__(256) void k_gemm(const u16* __restrict__ A, const u16* __restrict__ Wt,
                                              const float* __restrict__ bias, u16* __restrict__ C,
                                              int K, int N, int bx, int fuse) {
    __shared__ __align__(16) u16 As[128 * 32];
    __shared__ __align__(16) u16 Bs[128 * 32];
    int nwg = gridDim.x;
    int chunk = nwg >> 3;
    int swz = (blockIdx.x & 7) * chunk + (blockIdx.x >> 3);
    int tx = swz % bx, ty = swz / bx;
    int tid = threadIdx.x;
    int wid = tid >> 6, lane = tid & 63;
    int wr = wid >> 1, wc = wid & 1;
    int lo = lane & 15, hi = lane >> 4;
    size_t row0 = (size_t)ty * 128;
    size_t col0 = (size_t)tx * 128;

    f32x4 acc[4][4];
    #pragma unroll
    for (int m = 0; m < 4; ++m)
        #pragma unroll
        for (int n = 0; n < 4; ++n) acc[m][n] = {0.f, 0.f, 0.f, 0.f};

    const char* gA = (const char*)(A + row0 * K);
    const char* gB = (const char*)(Wt + col0 * K);
    size_t rs = (size_t)K * 2;
    int lin0 = tid * 16;
    int lin1 = lin0 + 4096;
    int rA0 = lin0 >> 6, cb0 = lin0 & 63;
    int rA1 = lin1 >> 6, cb1 = lin1 & 63;
    unsigned ldsOff = (unsigned)(wid << 10);

    for (int k0 = 0; k0 < K; k0 += 32) {
        __syncthreads();
        size_t kb = (size_t)k0 * 2;
        __builtin_amdgcn_global_load_lds(AS1(gA + (size_t)rA0 * rs + cb0 + kb),
                                         AS3((char*)As + ldsOff), 16, 0, 0);
        __builtin_amdgcn_global_load_lds(AS1(gA + (size_t)rA1 * rs + cb1 + kb),
                                         AS3((char*)As + 4096 + ldsOff), 16, 0, 0);
        __builtin_amdgcn_global_load_lds(AS1(gB + (size_t)rA0 * rs + cb0 + kb),
                                         AS3((char*)Bs + ldsOff), 16, 0, 0);
        __builtin_amdgcn_global_load_lds(AS1(gB + (size_t)rA1 * rs + cb1 + kb),
                                         AS3((char*)Bs + 4096 + ldsOff), 16, 0, 0);
        __syncthreads();
        half8 afr[4], bfr[4];
        #pragma unroll
        for (int m = 0; m < 4; ++m)
            afr[m] = *(const half8*)((const u16*)As + (wr * 64 + m * 16 + lo) * 32 + hi * 8);
        #pragma unroll
        for (int n = 0; n < 4; ++n)
            bfr[n] = *(const half8*)((const u16*)Bs + (wc * 64 + n * 16 + lo) * 32 + hi * 8);
        #pragma unroll
        for (int m = 0; m < 4; ++m)
            #pragma unroll
            for (int n = 0; n < 4; ++n)
                acc[m][n] = __builtin_amdgcn_mfma_f32_16x16x32_f16(afr[m], bfr[n], acc[m][n], 0, 0, 0);
    }
    #pragma unroll
    for (int m = 0; m < 4; ++m) {
        #pragma unroll
        for (int n = 0; n < 4; ++n) {
            #pragma unroll
            for (int r = 0; r < 4; ++r) {
                size_t row = row0 + wr * 64 + m * 16 + hi * 4 + r;
                size_t col = col0 + wc * 64 + n * 16 + lo;
                float v = acc[m][n][r];
                if (fuse) v = fmaxf(v + bias[col], 0.f);
                C[row * N + col] = f2b(v);
            }
        }
    }
}

// ---------- layer 7: fused BN6 + GEMV ----------
__global__ __launch_bounds__(256) void k_gemv(const u16* __restrict__ A, const float* __restrict__ w,
                                              const float* __restrict__ a, const float* __restrict__ b,
                                              float* __restrict__ y) {
    int row = blockIdx.x * 4 + (threadIdx.x >> 6);
    int lane = threadIdx.x & 63;
    const u16* h = A + (size_t)row * 256;
    float s = 0.f;
    #pragma unroll
    for (int j = 0; j < 4; ++j) {
        int c = lane + j * 64;
        s += (a[c] * b2f(h[c]) + b[c]) * w[c];
    }
    #pragma unroll
    for (int off = 32; off; off >>= 1) s += __shfl_down(s, off);
    if (lane == 0) y[row] = s;
}
__global__ void k_final(const float* __restrict__ y, const int* __restrict__ rowptr,
                        const int* __restrict__ csr_src, const float* __restrict__ csr_w,
                        const float* __restrict__ dinv, const int* __restrict__ batch,
                        const float* __restrict__ b7, float* __restrict__ out) {
    int i = blockIdx.x * 256 + threadIdx.x;
    if (i >= NN) return;
    float v = dinv[i] * dinv[i] * y[i];
    int r1 = rowptr[i + 1];
    for (int e = rowptr[i]; e < r1; ++e) v += csr_w[e] * y[csr_src[e]];
    atomicAdd(&out[batch[i]], v + b7[0]);
}
__global__ void k_sentinel(float* out, float v) {
    if (threadIdx.x == 0 && blockIdx.x == 0) out[0] = v;
}

// ---------- host ----------
static inline char* alignp(char* p) { return (char*)(((uintptr_t)p + 255) & ~(uintptr_t)255); }

extern "C" void kernel_launch(void* const* d_in, const int* in_sizes, int n_in,
                              void* d_out, int out_size, void* d_ws, size_t ws_size,
                              hipStream_t stream) {
    const float* x = (const float*)d_in[0];
    const int* ei = (const int*)d_in[1];
    const int* src = ei;
    const int* dst = ei + NE;
    const int* batch = (const int*)d_in[2];
    const float* W[7]; const float* bv[7];
    for (int i = 0; i < 7; ++i) { W[i] = (const float*)d_in[3 + 2 * i]; bv[i] = (const float*)d_in[4 + 2 * i]; }
    const float* g[6]; const float* be[6];
    for (int i = 0; i < 6; ++i) { g[i] = (const float*)d_in[17 + 2 * i]; be[i] = (const float*)d_in[18 + 2 * i]; }
    float* out = (float*)d_out;

    // workspace layout
    char* p = (char*)d_ws;
    u16* Abuf = (u16*)p; p += (size_t)NN * 4096 * 2;
    u16* Bbuf = (u16*)p; p += (size_t)NN * 2048 * 2;
    u16* xpad = (u16*)p; p += (size_t)NN * 512 * 2;
    u16* W1t = (u16*)p; p += (size_t)4096 * 512 * 2;
    u16* W2t = (u16*)p; p += (size_t)2048 * 4096 * 2;
    u16* W3t = (u16*)p; p += (size_t)1024 * 2048 * 2;
    u16* W4t = (u16*)p; p += (size_t)1024 * 1024 * 2;
    u16* W5t = (u16*)p; p += (size_t)2048 * 1024 * 2;
    u16* W6t = (u16*)p; p += (size_t)256 * 2048 * 2;
    p = alignp(p);
    int* degi = (int*)p; p += NN * 4;
    int* cursor = (int*)p; p += NN * 4;
    int* rowptr = (int*)p; p += (NN + 1) * 4; p = alignp(p);
    int* csr_src = (int*)p; p += NE * 4;
    float* csr_w = (float*)p; p += NE * 4;
    float* dinv = (float*)p; p += NN * 4;
    float* nrm = (float*)p; p += NE * 4;
    float* svec = (float*)p; p += NN * 4;
    float* s1 = (float*)p; p += 4096 * 4;
    float* s2 = (float*)p; p += 4096 * 4;
    float* bna = (float*)p; p += 4096 * 4;
    float* bnb = (float*)p; p += 4096 * 4;
    float* y = (float*)p; p += NN * 4;
    size_t need = (size_t)(p - (char*)d_ws);
    if (need > ws_size) {
        hipMemsetAsync(d_out, 0, NG * sizeof(float), stream);
        k_sentinel<<<1, 64, 0, stream>>>(out, (float)(ws_size >> 20));
        return;
    }

    (void)hipFuncSetAttribute((const void*)k_gemm256,
                              hipFuncAttributeMaxDynamicSharedMemorySize, 131072);

    // --- graph prep ---
    hipMemsetAsync(degi, 0, 2 * NN * sizeof(int), stream);  // degi + cursor
    k_degi<<<NE / 256, 256, 0, stream>>>(dst, degi);
    k_dinv<<<NN / 256, 256, 0, stream>>>(degi, dinv);
    k_nrm<<<NE / 256, 256, 0, stream>>>(src, dst, dinv, nrm);
    k_scan<<<1, 1024, 0, stream>>>(degi, rowptr);
    k_place<<<NE / 256, 256, 0, stream>>>(src, dst, nrm, rowptr, cursor, csr_src, csr_w);
    k_srow<<<NN / 256, 256, 0, stream>>>(rowptr, csr_w, dinv, svec);

    // --- upfront conversions ---
    k_x2b<<<(NN * 512) / 256, 256, 0, stream>>>(x, xpad);
    {
        dim3 b(32, 8);
        k_wt<<<dim3(16, 128), b, 0, stream>>>(W[0], W1t, 396, 512, 4096);
        k_wt<<<dim3(128, 64), b, 0, stream>>>(W[1], W2t, 4096, 4096, 2048);
        k_wt<<<dim3(64, 32), b, 0, stream>>>(W[2], W3t, 2048, 2048, 1024);
        k_wt<<<dim3(32, 32), b, 0, stream>>>(W[3], W4t, 1024, 1024, 1024);
        k_wt<<<dim3(32, 64), b, 0, stream>>>(W[4], W5t, 1024, 1024, 2048);
        k_wt<<<dim3(64, 8), b, 0, stream>>>(W[5], W6t, 2048, 2048, 256);
    }

    auto gemm = [&](const u16* A, const u16* Wt, const float* bias, u16* Cp, int K, int N, int fuse) {
        if (N >= 1024) {
            int bx = N / 256;
            k_gemm256<<<bx * (NN / 256), 512, 131072, stream>>>(A, Wt, bias, Cp, K, N, bx, fuse);
        } else {
            int bx = N / 128;
            k_gemm<<<bx * (NN / 128), 256, 0, stream>>>(A, Wt, bias, Cp, K, N, bx, fuse);
        }
    };
    auto agg = [&](const u16* in, u16* o, const float* bias, const float* av,
                   const float* bvv, int F, int mode) {
        if (F == 2048) k_agg<8><<<NN, 256, 0, stream>>>(in, o, rowptr, csr_src, csr_w, dinv, svec, bias, av, bvv, F, mode);
        else if (F == 1024) k_agg<4><<<NN, 256, 0, stream>>>(in, o, rowptr, csr_src, csr_w, dinv, svec, bias, av, bvv, F, mode);
        else if (F == 512) k_agg<2><<<NN, 256, 0, stream>>>(in, o, rowptr, csr_src, csr_w, dinv, svec, bias, av, bvv, F, mode);
        else k_agg<1><<<NN, 256, 0, stream>>>(in, o, rowptr, csr_src, csr_w, dinv, svec, bias, av, bvv, F, mode);
    };
    auto stats = [&](const u16* h, int F) {
        hipMemsetAsync(s1, 0, 2 * 4096 * sizeof(float), stream);   // s1+s2
        if (F == 4096) k_stats<8><<<dim3(2, NN / SROWS), 256, 0, stream>>>(h, s1, s2, F);
        else if (F == 2048) k_stats<8><<<dim3(1, NN / SROWS), 256, 0, stream>>>(h, s1, s2, F);
        else if (F == 1024) k_stats<4><<<dim3(1, NN / SROWS), 256, 0, stream>>>(h, s1, s2, F);
        else k_stats<1><<<dim3(1, NN / SROWS), 256, 0, stream>>>(h, s1, s2, F);
    };
    auto bnapply = [&](u16* h, int F, int li) {
        k_bnapply<<<(int)(((size_t)NN * F / 8) / 256), 256, 0, stream>>>(h, s1, s2, g[li], be[li], F);
    };

    // --- L1: 396(512) -> 4096, agg-first; BN1 applied (fused stats->apply) ---
    agg(xpad, Bbuf, nullptr, nullptr, nullptr, 512, 0);
    gemm(Bbuf, W1t, bv[0], Abuf, 512, 4096, 1);
    stats(Abuf, 4096);
    bnapply(Abuf, 4096, 0);

    // --- L2: 4096 -> 2048, gemm-first; BN2 applied ---
    gemm(Abuf, W2t, nullptr, Bbuf, 4096, 2048, 0);
    agg(Bbuf, Abuf, bv[1], nullptr, nullptr, 2048, 1);
    stats(Abuf, 2048);
    bnapply(Abuf, 2048, 1);

    // --- L3: 2048 -> 1024, gemm-first; BN3 applied ---
    gemm(Abuf, W3t, nullptr, Bbuf, 2048, 1024, 0);
    agg(Bbuf, Abuf, bv[2], nullptr, nullptr, 1024, 1);
    stats(Abuf, 1024);
    bnapply(Abuf, 1024, 2);

    // --- L4: 1024 -> 1024, gemm-first; BN4 left unapplied (folded into L5 agg) ---
    gemm(Abuf, W4t, nullptr, Bbuf, 1024, 1024, 0);
    agg(Bbuf, Abuf, bv[3], nullptr, nullptr, 1024, 1);
    stats(Abuf, 1024);
    k_bnab<<<1024 / 256, 256, 0, stream>>>(s1, s2, g[3], be[3], bna, bnb, 1024);

    // --- L5: 1024 -> 2048, agg-first with BN4 fold ---
    agg(Abuf, Bbuf, nullptr, bna, bnb, 1024, 2);
    gemm(Bbuf, W5t, bv[4], Abuf, 1024, 2048, 1);
    stats(Abuf, 2048);
    bnapply(Abuf, 2048, 4);

    // --- L6: 2048 -> 256, gemm-first (128^2 kernel); BN6 folded into GEMV ---
    gemm(Abuf, W6t, nullptr, Bbuf, 2048, 256, 0);
    agg(Bbuf, Abuf, bv[5], nullptr, nullptr, 256, 1);
    stats(Abuf, 256);
    k_bnab<<<1, 256, 0, stream>>>(s1, s2, g[5], be[5], bna, bnb, 256);

    // --- L7: 256 -> 1 with BN6 fused in GEMV, then agg + pool ---
    k_gemv<<<NN / 4, 256, 0, stream>>>(Abuf, W[6], bna, bnb, y);
    hipMemsetAsync(d_out, 0, NG * sizeof(float), stream);
    k_final<<<NN / 256, 256, 0, stream>>>(y, rowptr, csr_src, csr_w, dinv, batch, bv[6], out);
}

// Round 10
// 1315.760 us; speedup vs baseline: 1.1481x; 1.1425x over previous
//
#include <hip/hip_runtime.h>

// GCN: 7x GCNConv (first 6 with ReLU+BN training-mode), then global_add_pool.
// N=16384 nodes, E=131072 edges, 64 graphs. fp32 in/out, fp16 internal + MFMA.
// agg on the narrow side per layer (agg is linear).
// BN folds (fp16 headroom makes R4's bf16-failed fold safe):
//   BN1/2/3/5 -> next GEMM weights (a scales W rows; rank-1 s_i*(b@W) in agg)
//   BN4 -> L5 agg epilogue (mode 2), BN6 -> L7 GEMV registers.
// -> zero standalone BN-apply passes. Stats for L1/L5 fused into GEMM epilogue.
// GEMM: 256x256 8-phase, rotation swizzle (R9: bank conflicts = 0).

#define NN 16384
#define NE 131072
#define NG 64

typedef unsigned int u32;
typedef unsigned short u16;
typedef __attribute__((ext_vector_type(8))) _Float16 half8;
typedef __attribute__((ext_vector_type(4))) float f32x4;
typedef __attribute__((ext_vector_type(8))) u16 us8;
typedef __attribute__((ext_vector_type(4))) u16 us4;
typedef __attribute__((ext_vector_type(2))) u16 us2;

#define AS1(p) ((const __attribute__((address_space(1))) void*)(p))
#define AS3(p) ((__attribute__((address_space(3))) void*)(p))

__device__ __forceinline__ float b2f(u16 h) {
    _Float16 x = __builtin_bit_cast(_Float16, h);
    return (float)x;
}
__device__ __forceinline__ u16 f2b(float f) {
    _Float16 x = (_Float16)f;
    return __builtin_bit_cast(u16, x);
}

template <int VW> struct VecU;
template <> struct VecU<8> { typedef us8 T; };
template <> struct VecU<4> { typedef us4 T; };
template <> struct VecU<2> { typedef us2 T; };
template <> struct VecU<1> { typedef u16 T; };

template <int VW>
__device__ __forceinline__ void loadf(const u16* p, float* f) {
    typename VecU<VW>::T v = *(const typename VecU<VW>::T*)p;
    if constexpr (VW == 1) {
        f[0] = b2f((u16)v);
    } else {
        #pragma unroll
        for (int j = 0; j < VW; ++j) f[j] = b2f(v[j]);
    }
}
template <int VW>
__device__ __forceinline__ void storef(u16* p, const float* f) {
    typename VecU<VW>::T v;
    if constexpr (VW == 1) {
        v = f2b(f[0]);
    } else {
        #pragma unroll
        for (int j = 0; j < VW; ++j) v[j] = f2b(f[j]);
    }
    *(typename VecU<VW>::T*)p = v;
}

// ---------- graph prep ----------
__global__ void k_degi(const int* __restrict__ dst, int* __restrict__ deg) {
    int e = blockIdx.x * 256 + threadIdx.x;
    if (e < NE) atomicAdd(&deg[dst[e]], 1);
}
__global__ void k_dinv(const int* __restrict__ deg, float* __restrict__ dinv) {
    int i = blockIdx.x * 256 + threadIdx.x;
    if (i < NN) dinv[i] = rsqrtf((float)(deg[i] + 1));   // +1 self loop
}
__global__ void k_nrm(const int* __restrict__ src, const int* __restrict__ dst,
                      const float* __restrict__ dinv, float* __restrict__ nrm) {
    int e = blockIdx.x * 256 + threadIdx.x;
    if (e < NE) nrm[e] = dinv[src[e]] * dinv[dst[e]];
}
__global__ __launch_bounds__(1024) void k_scan(const int* __restrict__ deg, int* __restrict__ rowptr) {
    __shared__ int part[1024];
    int t = threadIdx.x;
    int base = t * 16;
    int s = 0;
    #pragma unroll
    for (int j = 0; j < 16; ++j) s += deg[base + j];
    part[t] = s;
    __syncthreads();
    for (int off = 1; off < 1024; off <<= 1) {
        int v = 0;
        if (t >= off) v = part[t - off];
        __syncthreads();
        part[t] += v;
        __syncthreads();
    }
    int run = part[t] - s;  // exclusive prefix
    for (int j = 0; j < 16; ++j) { rowptr[base + j] = run; run += deg[base + j]; }
    if (t == 1023) rowptr[NN] = run;
}
__global__ void k_place(const int* __restrict__ src, const int* __restrict__ dst,
                        const float* __restrict__ nrm, const int* __restrict__ rowptr,
                        int* __restrict__ cursor, int* __restrict__ csr_src,
                        float* __restrict__ csr_w) {
    int e = blockIdx.x * 256 + threadIdx.x;
    if (e >= NE) return;
    int d = dst[e];
    int p = rowptr[d] + atomicAdd(&cursor[d], 1);
    csr_src[p] = src[e];
    csr_w[p] = nrm[e];
}
// s_i = dinv_i^2 + sum of edge weights into i  (agg-operator row sum)
__global__ void k_srow(const int* __restrict__ rowptr, const float* __restrict__ csr_w,
                       const float* __restrict__ dinv, float* __restrict__ svec) {
    int i = blockIdx.x * 256 + threadIdx.x;
    if (i >= NN) return;
    float s = dinv[i] * dinv[i];
    int r1 = rowptr[i + 1];
    for (int e = rowptr[i]; e < r1; ++e) s += csr_w[e];
    svec[i] = s;
}

// ---------- conversions ----------
__global__ void k_x2b(const float* __restrict__ x, u16* __restrict__ xp) {
    int idx = blockIdx.x * 256 + threadIdx.x;   // over NN*512
    int i = idx >> 9, c = idx & 511;
    float v = (c < 396) ? x[(size_t)i * 396 + c] : 0.f;
    xp[idx] = f2b(v);
}
// Wt[n][k] = f16(scale[k]*W[k][n]); also rv[n] += sum_k bsh[k]*W[k][n] (rank-1 BN shift).
// scale/bsh/rv may be null (unscaled).
__global__ void k_wt(const float* __restrict__ W, u16* __restrict__ Wt,
                     const float* __restrict__ scale, const float* __restrict__ bsh,
                     float* __restrict__ rv, int Ksrc, int Kpad, int N) {
    __shared__ float t[32][33];
    __shared__ float rbuf[8][32];
    int k0 = blockIdx.x * 32, n0 = blockIdx.y * 32;
    int tx = threadIdx.x, ty = threadIdx.y;
    float rvp = 0.f;
    #pragma unroll
    for (int j = 0; j < 4; ++j) {
        int k = k0 + ty + j * 8;
        float v = 0.f;
        if (k < Ksrc) v = W[(size_t)k * N + n0 + tx];
        if (rv) rvp += bsh[k] * v;
        t[ty + j * 8][tx] = scale ? v * scale[k] : v;
    }
    if (rv) rbuf[ty][tx] = rvp;
    __syncthreads();
    #pragma unroll
    for (int j = 0; j < 4; ++j) {
        int n = n0 + ty + j * 8;
        int k = k0 + tx;
        Wt[(size_t)n * Kpad + k] = f2b(t[tx][ty + j * 8]);
    }
    if (rv && ty == 0) {
        float s = 0.f;
        #pragma unroll
        for (int j = 0; j < 8; ++j) s += rbuf[j][tx];
        atomicAdd(&rv[n0 + tx], s);
    }
}

// ---------- CSR gather aggregation (one block per node) ----------
// mode 0: out = acc
// mode 1: out = relu(acc + s_i*rv[c] + bias[c])   (rv = folded BN shift through W)
// mode 2: out = av[c]*acc + s_i*bvv[c]            (BN of input folded through agg)
template <int VW>
__global__ __launch_bounds__(256) void k_agg(const u16* __restrict__ in, u16* __restrict__ out,
                                             const int* __restrict__ rowptr,
                                             const int* __restrict__ csr_src,
                                             const float* __restrict__ csr_w,
                                             const float* __restrict__ dinv,
                                             const float* __restrict__ svec,
                                             const float* __restrict__ bias,
                                             const float* __restrict__ rv,
                                             const float* __restrict__ av,
                                             const float* __restrict__ bvv,
                                             int F, int mode) {
    int i = blockIdx.x;
    int c0 = threadIdx.x * VW;
    float acc[VW];
    float d2 = dinv[i]; d2 *= d2;
    {
        float v[VW];
        loadf<VW>(in + (size_t)i * F + c0, v);
        #pragma unroll
        for (int j = 0; j < VW; ++j) acc[j] = d2 * v[j];
    }
    int r0 = rowptr[i], r1 = rowptr[i + 1];
    for (int e = r0; e < r1; ++e) {
        int s = csr_src[e];
        float w = csr_w[e];
        float v[VW];
        loadf<VW>(in + (size_t)s * F + c0, v);
        #pragma unroll
        for (int j = 0; j < VW; ++j) acc[j] += w * v[j];
    }
    if (mode == 1) {
        float si = svec[i];
        #pragma unroll
        for (int j = 0; j < VW; ++j)
            acc[j] = fmaxf(acc[j] + si * rv[c0 + j] + bias[c0 + j], 0.f);
    } else if (mode == 2) {
        float si = svec[i];
        #pragma unroll
        for (int j = 0; j < VW; ++j) acc[j] = av[c0 + j] * acc[j] + si * bvv[c0 + j];
    }
    storef<VW>(out + (size_t)i * F + c0, acc);
}

// ---------- BN stats (for agg-output layers) ----------
#define SROWS 128
template <int VW>
__global__ __launch_bounds__(256) void k_stats(const u16* __restrict__ h, float* __restrict__ s1,
                                               float* __restrict__ s2, int F) {
    int c0 = (blockIdx.x * 256 + threadIdx.x) * VW;
    int r0 = blockIdx.y * SROWS;
    float s[VW], q[VW];
    #pragma unroll
    for (int j = 0; j < VW; ++j) { s[j] = 0.f; q[j] = 0.f; }
    for (int r = r0; r < r0 + SROWS; ++r) {
        float v[VW];
        loadf<VW>(h + (size_t)r * F + c0, v);
        #pragma unroll
        for (int j = 0; j < VW; ++j) { s[j] += v[j]; q[j] += v[j] * v[j]; }
    }
    #pragma unroll
    for (int j = 0; j < VW; ++j) {
        atomicAdd(&s1[c0 + j], s[j]);
        atomicAdd(&s2[c0 + j], q[j]);
    }
}
__global__ void k_bnab(const float* __restrict__ s1, const float* __restrict__ s2,
                       const float* __restrict__ g, const float* __restrict__ be,
                       float* __restrict__ a, float* __restrict__ b, int F) {
    int c = blockIdx.x * 256 + threadIdx.x;
    if (c >= F) return;
    float m = s1[c] * (1.f / NN);
    float v = s2[c] * (1.f / NN) - m * m;
    float aa = g[c] * rsqrtf(v + 1e-5f);
    a[c] = aa;
    b[c] = be[c] - m * aa;
}

// ================= 256x256 8-phase MFMA GEMM (f16) =================
// C[M,N] = A[M,K] @ Wt[N,K]^T. 512 thr = 8 waves (2 Mx4 N), BK=64,
// LDS 128 KiB: A[2buf][2Khalf][16KiB] @0, B same @64KiB.
// Rotation perm (R9, conflict-free): granule c of row r at LDS granule (c+(r>>1))&3;
// source pre-permuted, read lane (hi,lo) uses (hi+(lo>>1))&3.
// Optional fused column stats (s1/s2 non-null): per-thread partials -> LDS
// atomic reduce -> 256x2 global atomics per block.
__device__ __forceinline__ void stage16k(const char* gbase, size_t rs, int ktile, int h,
                                         char* slot, int tid) {
    size_t colb = (size_t)ktile * 128 + h * 64;
    #pragma unroll
    for (int i = 0; i < 2; ++i) {
        int G = i * 512 + tid;
        int r = G >> 2;
        int c = ((G & 3) - (r >> 1)) & 3;   // inverse of storage rotation
        __builtin_amdgcn_global_load_lds(AS1(gbase + (size_t)r * rs + colb + c * 16),
                                         AS3(slot + i * 8192 + ((tid >> 6) << 10)), 16, 0, 0);
    }
}

__global__ __launch_bounds__(512, 2) void k_gemm256(const u16* __restrict__ A,
                                                    const u16* __restrict__ Wt,
                                                    const float* __restrict__ bias,
                                                    u16* __restrict__ C,
                                                    float* __restrict__ s1,
                                                    float* __restrict__ s2,
                                                    int K, int N, int bx, int fuse) {
    extern __shared__ __align__(16) char smem[];
    int nwg = gridDim.x;
    int chunk = nwg >> 3;
    int swz = (blockIdx.x & 7) * chunk + (blockIdx.x >> 3);
    int tx = swz % bx, ty = swz / bx;
    int tid = threadIdx.x;
    int wid = tid >> 6, lane = tid & 63;
    int wr = wid >> 2, wc = wid & 3;         // 2 x 4 wave grid
    int lo = lane & 15, hi = lane >> 4;
    int sw = (((hi + (lo >> 1)) & 3) << 4);  // rotation swizzle (conflict-free)
    size_t row0 = (size_t)ty * 256;
    size_t col0 = (size_t)tx * 256;
    int nkt = K >> 6;

    const char* gA = (const char*)(A + row0 * K);
    const char* gB = (const char*)(Wt + col0 * K);
    size_t rs = (size_t)K * 2;

    const char* aA = smem + wr * 8192 + lo * 64 + sw;
    const char* bA = smem + 65536 + wc * 4096 + lo * 64 + sw;
#define ASL(b, h) (smem + (((b) * 2 + (h)) << 14))
#define BSL(b, h) (smem + 65536 + (((b) * 2 + (h)) << 14))

    f32x4 acc[8][4];
    #pragma unroll
    for (int m = 0; m < 8; ++m)
        #pragma unroll
        for (int n = 0; n < 4; ++n) acc[m][n] = {0.f, 0.f, 0.f, 0.f};
    half8 af[4], bf[4];

    // ---- prologue: kt0 fully + kt1 h0 ----
    stage16k(gA, rs, 0, 0, ASL(0, 0), tid);
    stage16k(gB, rs, 0, 0, BSL(0, 0), tid);
    stage16k(gA, rs, 0, 1, ASL(0, 1), tid);
    stage16k(gB, rs, 0, 1, BSL(0, 1), tid);
    stage16k(gA, rs, 1, 0, ASL(1, 0), tid);
    stage16k(gB, rs, 1, 0, BSL(1, 0), tid);
    asm volatile("s_waitcnt vmcnt(4)" ::: "memory");
    __builtin_amdgcn_sched_barrier(0);
    __builtin_amdgcn_s_barrier();

#define DS_LOADS(KK, MH)                                                                   \
    {                                                                                      \
        _Pragma("unroll") for (int j = 0; j < 4; ++j)                                      \
            af[j] = *(const half8*)(aA + buf * 32768 + (KK) * 16384 + (MH) * 4096 + j * 1024); \
        if ((MH) == 0) {                                                                   \
            _Pragma("unroll") for (int j = 0; j < 4; ++j)                                  \
                bf[j] = *(const half8*)(bA + buf * 32768 + (KK) * 16384 + j * 1024);       \
        }                                                                                  \
    }
#define MFMA_PHASE(MH)                                                                     \
    {                                                                                      \
        asm volatile("" ::: "memory");                                                     \
        __builtin_amdgcn_s_barrier();                                                      \
        __builtin_amdgcn_s_setprio(1);                                                     \
        _Pragma("unroll") for (int j = 0; j < 4; ++j)                                      \
            _Pragma("unroll") for (int n = 0; n < 4; ++n)                                  \
                acc[(MH) * 4 + j][n] = __builtin_amdgcn_mfma_f32_16x16x32_f16(             \
                    af[j], bf[n], acc[(MH) * 4 + j][n], 0, 0, 0);                          \
        __builtin_amdgcn_s_setprio(0);                                                     \
    }
#define END_BARRIER                                                                        \
    {                                                                                      \
        asm volatile("" ::: "memory");                                                     \
        __builtin_amdgcn_s_barrier();                                                      \
    }

    for (int kt = 0; kt < nkt; ++kt) {
        int buf = kt & 1;
        DS_LOADS(0, 0);
        if (kt + 1 < nkt) {
            stage16k(gA, rs, kt + 1, 1, ASL(buf ^ 1, 1), tid);
            stage16k(gB, rs, kt + 1, 1, BSL(buf ^ 1, 1), tid);
        }
        MFMA_PHASE(0);
        END_BARRIER;
        DS_LOADS(0, 1);
        MFMA_PHASE(1);
        END_BARRIER;
        DS_LOADS(1, 0);
        if (kt + 2 < nkt) stage16k(gA, rs, kt + 2, 0, ASL(buf, 0), tid);
        MFMA_PHASE(0);
        END_BARRIER;
        DS_LOADS(1, 1);
        if (kt + 2 < nkt) stage16k(gB, rs, kt + 2, 0, BSL(buf, 0), tid);
        MFMA_PHASE(1);
        asm volatile("s_waitcnt vmcnt(4)" ::: "memory");
        __builtin_amdgcn_sched_barrier(0);
        END_BARRIER;
    }

    // ---- epilogue (+ optional fused column stats) ----
    float cs[4] = {0.f, 0.f, 0.f, 0.f}, cq[4] = {0.f, 0.f, 0.f, 0.f};
    #pragma unroll
    for (int fm = 0; fm < 8; ++fm) {
        #pragma unroll
        for (int n = 0; n < 4; ++n) {
            #pragma unroll
            for (int r = 0; r < 4; ++r) {
                size_t row = row0 + wr * 128 + fm * 16 + hi * 4 + r;
                size_t col = col0 + wc * 64 + n * 16 + lo;
                float v = acc[fm][n][r];
                if (fuse) v = fmaxf(v + bias[col], 0.f);
                C[row * N + col] = f2b(v);
                cs[n] += v;
                cq[n] += v * v;
            }
        }
    }
    if (s1) {
        asm volatile("s_waitcnt vmcnt(0)" ::: "memory");
        __syncthreads();
        float* sp = (float*)smem;        // 512 floats: [localcol][0]=sum,[1]=sumsq
        sp[tid] = 0.f;
        __syncthreads();
        #pragma unroll
        for (int n = 0; n < 4; ++n) {
            int lc = wc * 64 + n * 16 + lo;
            atomicAdd(&sp[lc * 2], cs[n]);
            atomicAdd(&sp[lc * 2 + 1], cq[n]);
        }
        __syncthreads();
        if (tid < 256) {
            atomicAdd(&s1[col0 + tid], sp[tid * 2]);
            atomicAdd(&s2[col0 + tid], sp[tid * 2 + 1]);
        }
    }
#undef DS_LOADS
#undef MFMA_PHASE
#undef END_BARRIER
#undef ASL
#undef BSL
}

// ---------- 128x128 m97-style GEMM (kept for N=256 layer) ----------
__global__ __launch_bounds__(256) void k_gemm(const u16* __restrict__ A, const u16* __restrict__ Wt,
                                              const float* __restrict__ bias, u16* __restrict__ C,
                                              int K, int N, int bx, int fuse) {
    __shared__ __align__(16) u16 As[128 * 32];
    __shared__ __align__(16) u16 Bs[128 * 32];
    int nwg = gridDim.x;
    int chunk = nwg >> 3;
    int swz = (blockIdx.x & 7) * chunk + (blockIdx.x >> 3);
    int tx = swz % bx, ty = swz / bx;
    int tid = threadIdx.x;
    int wid = tid >> 6, lane = tid & 63;
    int wr = wid >> 1, wc = wid & 1;
    int lo = lane & 15, hi = lane >> 4;
    size_t row0 = (size_t)ty * 128;
    size_t col0 = (size_t)tx * 128;

    f32x4 acc[4][4];
    #pragma unroll
    for (int m = 0; m < 4; ++m)
        #pragma unroll
        for (int n = 0; n < 4; ++n) acc[m][n] = {0.f, 0.f, 0.f, 0.f};

    const char* gA = (const char*)(A + row0 * K);
    const char* gB = (const char*)(Wt + col0 * K);
    size_t rs = (size_t)K * 2;
    int lin0 = tid * 16;
    int lin1 = lin0 + 4096;
    int rA0 = lin0 >> 6, cb0 = lin0 & 63;
    int rA1 = lin1 >> 6, cb1 = lin1 & 63;
    unsigned ldsOff = (unsigned)(wid << 10);

    for (int k0 = 0; k0 < K; k0 += 32) {
        __syncthreads();
        size_t kb = (size_t)k0 * 2;
        __builtin_amdgcn_global_load_lds(AS1(gA + (size_t)rA0 * rs + cb0 + kb),
                                         AS3((char*)As + ldsOff), 16, 0, 0);
        __builtin_amdgcn_global_load_lds(AS1(gA + (size_t)rA1 * rs + cb1 + kb),
                                         AS3((char*)As + 4096 + ldsOff), 16, 0, 0);
        __builtin_amdgcn_global_load_lds(AS1(gB + (size_t)rA0 * rs + cb0 + kb),
                                         AS3((char*)Bs + ldsOff), 16, 0, 0);
        __builtin_amdgcn_global_load_lds(AS1(gB + (size_t)rA1 * rs + cb1 + kb),
                                         AS3((char*)Bs + 4096 + ldsOff), 16, 0, 0);
        __syncthreads();
        half8 afr[4], bfr[4];
        #pragma unroll
        for (int m = 0; m < 4; ++m)
            afr[m] = *(const half8*)((const u16*)As + (wr * 64 + m * 16 + lo) * 32 + hi * 8);
        #pragma unroll
        for (int n = 0; n < 4; ++n)
            bfr[n] = *(const half8*)((const u16*)Bs + (wc * 64 + n * 16 + lo) * 32 + hi * 8);
        #pragma unroll
        for (int m = 0; m < 4; ++m)
            #pragma unroll
            for (int n = 0; n < 4; ++n)
                acc[m][n] = __builtin_amdgcn_mfma_f32_16x16x32_f16(afr[m], bfr[n], acc[m][n], 0, 0, 0);
    }
    #pragma unroll
    for (int m = 0; m < 4; ++m) {
        #pragma unroll
        for (int n = 0; n < 4; ++n) {
            #pragma unroll
            for (int r = 0; r < 4; ++r) {
                size_t row = row0 + wr * 64 + m * 16 + hi * 4 + r;
                size_t col = col0 + wc * 64 + n * 16 + lo;
                float v = acc[m][n][r];
                if (fuse) v = fmaxf(v + bias[col], 0.f);
                C[row * N + col] = f2b(v);
            }
        }
    }
}

// ---------- layer 7: fused BN6 + GEMV ----------
__global__ __launch_bounds__(256) void k_gemv(const u16* __restrict__ A, const float* __restrict__ w,
                                              const float* __restrict__ a, const float* __restrict__ b,
                                              float* __restrict__ y) {
    int row = blockIdx.x * 4 + (threadIdx.x >> 6);
    int lane = threadIdx.x & 63;
    const u16* h = A + (size_t)row * 256;
    float s = 0.f;
    #pragma unroll
    for (int j = 0; j < 4; ++j) {
        int c = lane + j * 64;
        s += (a[c] * b2f(h[c]) + b[c]) * w[c];
    }
    #pragma unroll
    for (int off = 32; off; off >>= 1) s += __shfl_down(s, off);
    if (lane == 0) y[row] = s;
}
__global__ void k_final(const float* __restrict__ y, const int* __restrict__ rowptr,
                        const int* __restrict__ csr_src, const float* __restrict__ csr_w,
                        const float* __restrict__ dinv, const int* __restrict__ batch,
                        const float* __restrict__ b7, float* __restrict__ out) {
    int i = blockIdx.x * 256 + threadIdx.x;
    if (i >= NN) return;
    float v = dinv[i] * dinv[i] * y[i];
    int r1 = rowptr[i + 1];
    for (int e = rowptr[i]; e < r1; ++e) v += csr_w[e] * y[csr_src[e]];
    atomicAdd(&out[batch[i]], v + b7[0]);
}
__global__ void k_sentinel(float* out, float v) {
    if (threadIdx.x == 0 && blockIdx.x == 0) out[0] = v;
}

// ---------- host ----------
static inline char* alignp(char* p) { return (char*)(((uintptr_t)p + 255) & ~(uintptr_t)255); }

extern "C" void kernel_launch(void* const* d_in, const int* in_sizes, int n_in,
                              void* d_out, int out_size, void* d_ws, size_t ws_size,
                              hipStream_t stream) {
    const float* x = (const float*)d_in[0];
    const int* ei = (const int*)d_in[1];
    const int* src = ei;
    const int* dst = ei + NE;
    const int* batch = (const int*)d_in[2];
    const float* W[7]; const float* bv[7];
    for (int i = 0; i < 7; ++i) { W[i] = (const float*)d_in[3 + 2 * i]; bv[i] = (const float*)d_in[4 + 2 * i]; }
    const float* g[6]; const float* be[6];
    for (int i = 0; i < 6; ++i) { g[i] = (const float*)d_in[17 + 2 * i]; be[i] = (const float*)d_in[18 + 2 * i]; }
    float* out = (float*)d_out;

    // workspace layout
    char* p = (char*)d_ws;
    u16* Abuf = (u16*)p; p += (size_t)NN * 4096 * 2;
    u16* Bbuf = (u16*)p; p += (size_t)NN * 2048 * 2;
    u16* xpad = (u16*)p; p += (size_t)NN * 512 * 2;
    u16* W1t = (u16*)p; p += (size_t)4096 * 512 * 2;
    u16* W2t = (u16*)p; p += (size_t)2048 * 4096 * 2;
    u16* W3t = (u16*)p; p += (size_t)1024 * 2048 * 2;
    u16* W4t = (u16*)p; p += (size_t)1024 * 1024 * 2;
    u16* W5t = (u16*)p; p += (size_t)2048 * 1024 * 2;
    u16* W6t = (u16*)p; p += (size_t)256 * 2048 * 2;
    p = alignp(p);
    int* degi = (int*)p; p += NN * 4;
    int* cursor = (int*)p; p += NN * 4;
    int* rowptr = (int*)p; p += (NN + 1) * 4; p = alignp(p);
    int* csr_src = (int*)p; p += NE * 4;
    float* csr_w = (float*)p; p += NE * 4;
    float* dinv = (float*)p; p += NN * 4;
    float* nrm = (float*)p; p += NE * 4;
    float* svec = (float*)p; p += NN * 4;
    float* s1 = (float*)p; p += 4096 * 4;
    float* s2 = (float*)p; p += 4096 * 4;
    float* bna = (float*)p; p += 4096 * 4;
    float* bnb = (float*)p; p += 4096 * 4;
    float* rv = (float*)p; p += 4096 * 4;
    float* y = (float*)p; p += NN * 4;
    size_t need = (size_t)(p - (char*)d_ws);
    if (need > ws_size) {
        hipMemsetAsync(d_out, 0, NG * sizeof(float), stream);
        k_sentinel<<<1, 64, 0, stream>>>(out, (float)(ws_size >> 20));
        return;
    }

    (void)hipFuncSetAttribute((const void*)k_gemm256,
                              hipFuncAttributeMaxDynamicSharedMemorySize, 131072);

    // --- graph prep ---
    hipMemsetAsync(degi, 0, 2 * NN * sizeof(int), stream);  // degi + cursor
    k_degi<<<NE / 256, 256, 0, stream>>>(dst, degi);
    k_dinv<<<NN / 256, 256, 0, stream>>>(degi, dinv);
    k_nrm<<<NE / 256, 256, 0, stream>>>(src, dst, dinv, nrm);
    k_scan<<<1, 1024, 0, stream>>>(degi, rowptr);
    k_place<<<NE / 256, 256, 0, stream>>>(src, dst, nrm, rowptr, cursor, csr_src, csr_w);
    k_srow<<<NN / 256, 256, 0, stream>>>(rowptr, csr_w, dinv, svec);

    // --- input + unscaled weight conversions ---
    k_x2b<<<(NN * 512) / 256, 256, 0, stream>>>(x, xpad);
    dim3 wtb(32, 8);
    k_wt<<<dim3(16, 128), wtb, 0, stream>>>(W[0], W1t, nullptr, nullptr, nullptr, 396, 512, 4096);
    k_wt<<<dim3(32, 64), wtb, 0, stream>>>(W[4], W5t, nullptr, nullptr, nullptr, 1024, 1024, 2048);

    auto gemm256 = [&](const u16* A, const u16* Wt, const float* bias, u16* Cp,
                       float* st1, float* st2, int K, int N, int fuse) {
        int bx = N / 256;
        k_gemm256<<<bx * (NN / 256), 512, 131072, stream>>>(A, Wt, bias, Cp, st1, st2, K, N, bx, fuse);
    };
    auto agg = [&](const u16* in, u16* o, const float* bias, const float* rvp,
                   const float* av, const float* bvv, int F, int mode) {
        if (F == 2048) k_agg<8><<<NN, 256, 0, stream>>>(in, o, rowptr, csr_src, csr_w, dinv, svec, bias, rvp, av, bvv, F, mode);
        else if (F == 1024) k_agg<4><<<NN, 256, 0, stream>>>(in, o, rowptr, csr_src, csr_w, dinv, svec, bias, rvp, av, bvv, F, mode);
        else if (F == 512) k_agg<2><<<NN, 256, 0, stream>>>(in, o, rowptr, csr_src, csr_w, dinv, svec, bias, rvp, av, bvv, F, mode);
        else k_agg<1><<<NN, 256, 0, stream>>>(in, o, rowptr, csr_src, csr_w, dinv, svec, bias, rvp, av, bvv, F, mode);
    };
    auto stats = [&](const u16* h, int F) {
        hipMemsetAsync(s1, 0, 2 * 4096 * sizeof(float), stream);   // s1+s2 (contiguous)
        if (F == 2048) k_stats<8><<<dim3(1, NN / SROWS), 256, 0, stream>>>(h, s1, s2, F);
        else if (F == 1024) k_stats<4><<<dim3(1, NN / SROWS), 256, 0, stream>>>(h, s1, s2, F);
        else k_stats<1><<<dim3(1, NN / SROWS), 256, 0, stream>>>(h, s1, s2, F);
    };
    auto bnab = [&](int li, int F) {
        k_bnab<<<(F + 255) / 256, 256, 0, stream>>>(s1, s2, g[li], be[li], bna, bnb, F);
    };
    // scaled weight transpose with rank-1 shift accumulation (BN fold)
    auto wts = [&](const float* Wp, u16* Wtp, int K, int N) {
        hipMemsetAsync(rv, 0, N * sizeof(float), stream);
        k_wt<<<dim3(K / 32, N / 32), wtb, 0, stream>>>(Wp, Wtp, bna, bnb, rv, K, K, N);
    };

    // --- L1: 396(512) -> 4096, agg-first; stats fused in GEMM epilogue ---
    agg(xpad, Bbuf, nullptr, nullptr, nullptr, nullptr, 512, 0);
    hipMemsetAsync(s1, 0, 2 * 4096 * sizeof(float), stream);
    gemm256(Bbuf, W1t, bv[0], Abuf, s1, s2, 512, 4096, 1);
    bnab(0, 4096);                                          // BN1 -> bna,bnb

    // --- L2: 4096 -> 2048; BN1 folded into W2 + rank-1 rv in agg ---
    wts(W[1], W2t, 4096, 2048);
    gemm256(Abuf, W2t, nullptr, Bbuf, nullptr, nullptr, 4096, 2048, 0);
    agg(Bbuf, Abuf, bv[1], rv, nullptr, nullptr, 2048, 1);
    stats(Abuf, 2048);
    bnab(1, 2048);                                          // BN2

    // --- L3: 2048 -> 1024; BN2 folded into W3 ---
    wts(W[2], W3t, 2048, 1024);
    gemm256(Abuf, W3t, nullptr, Bbuf, nullptr, nullptr, 2048, 1024, 0);
    agg(Bbuf, Abuf, bv[2], rv, nullptr, nullptr, 1024, 1);
    stats(Abuf, 1024);
    bnab(2, 1024);                                          // BN3

    // --- L4: 1024 -> 1024; BN3 folded into W4; BN4 stays unapplied ---
    wts(W[3], W4t, 1024, 1024);
    gemm256(Abuf, W4t, nullptr, Bbuf, nullptr, nullptr, 1024, 1024, 0);
    agg(Bbuf, Abuf, bv[3], rv, nullptr, nullptr, 1024, 1);
    stats(Abuf, 1024);
    bnab(3, 1024);                                          // BN4 -> bna,bnb

    // --- L5: 1024 -> 2048, agg-first with BN4 fold (mode 2); stats fused ---
    agg(Abuf, Bbuf, nullptr, nullptr, bna, bnb, 1024, 2);
    hipMemsetAsync(s1, 0, 2 * 4096 * sizeof(float), stream);
    gemm256(Bbuf, W5t, bv[4], Abuf, s1, s2, 1024, 2048, 1);
    bnab(4, 2048);                                          // BN5

    // --- L6: 2048 -> 256; BN5 folded into W6 (128^2 GEMM) ---
    wts(W[5], W6t, 2048, 256);
    k_gemm<<<(256 / 128) * (NN / 128), 256, 0, stream>>>(Abuf, W6t, nullptr, Bbuf, 2048, 256, 256 / 128, 0);
    agg(Bbuf, Abuf, bv[5], rv, nullptr, nullptr, 256, 1);
    stats(Abuf, 256);
    bnab(5, 256);                                           // BN6 -> bna,bnb

    // --- L7: 256 -> 1 with BN6 fused in GEMV, then agg + pool ---
    k_gemv<<<NN / 4, 256, 0, stream>>>(Abuf, W[6], bna, bnb, y);
    hipMemsetAsync(d_out, 0, NG * sizeof(float), stream);
    k_final<<<NN / 256, 256, 0, stream>>>(y, rowptr, csr_src, csr_w, dinv, batch, bv[6], out);
}